// Round 13
// baseline (3016.036 us; speedup 1.0000x reference)
//
#include <hip/hip_runtime.h>
#include <math.h>

#define BB 64
#define SS 512
#define EE 256
#define HH 512

// ---------------------------------------------------------------------------
// Projection GEMM (layer 0): out[m][n] = sum_k A[m][k]*Wih[n][k] + b1 + b2
// ---------------------------------------------------------------------------
template <int K>
__global__ __launch_bounds__(256) void k_proj(const float* __restrict__ Ain,
                                              const int* __restrict__ src,
                                              const float* __restrict__ emb,
                                              const float* __restrict__ Wih,
                                              const float* __restrict__ b1,
                                              const float* __restrict__ b2,
                                              float* __restrict__ out) {
    __shared__ __align__(16) float As[16][68];
    __shared__ __align__(16) float Bs[16][68];
    int tid = threadIdx.x;
    int m0 = blockIdx.x * 64;
    int n0 = blockIdx.y * 64;
    int tx = tid & 15, ty = tid >> 4;
    int lr = tid >> 2;
    int lc = (tid & 3) * 4;

    const float* arow;
    if (src) arow = emb + (size_t)src[m0 + lr] * EE;
    else     arow = Ain + (size_t)(m0 + lr) * K;
    const float* brow = Wih + (size_t)(n0 + lr) * K;

    float acc[4][4] = {};

    for (int k0 = 0; k0 < K; k0 += 16) {
        float4 av = *(const float4*)(arow + k0 + lc);
        float4 bv = *(const float4*)(brow + k0 + lc);
        __syncthreads();
        As[lc + 0][lr] = av.x; As[lc + 1][lr] = av.y;
        As[lc + 2][lr] = av.z; As[lc + 3][lr] = av.w;
        Bs[lc + 0][lr] = bv.x; Bs[lc + 1][lr] = bv.y;
        Bs[lc + 2][lr] = bv.z; Bs[lc + 3][lr] = bv.w;
        __syncthreads();
#pragma unroll
        for (int k = 0; k < 16; ++k) {
            float4 a = *(const float4*)&As[k][ty * 4];
            float4 b = *(const float4*)&Bs[k][tx * 4];
            acc[0][0] += a.x * b.x; acc[0][1] += a.x * b.y;
            acc[0][2] += a.x * b.z; acc[0][3] += a.x * b.w;
            acc[1][0] += a.y * b.x; acc[1][1] += a.y * b.y;
            acc[1][2] += a.y * b.z; acc[1][3] += a.y * b.w;
            acc[2][0] += a.z * b.x; acc[2][1] += a.z * b.y;
            acc[2][2] += a.z * b.z; acc[2][3] += a.z * b.w;
            acc[3][0] += a.w * b.x; acc[3][1] += a.w * b.y;
            acc[3][2] += a.w * b.z; acc[3][3] += a.w * b.w;
        }
    }

    int n = n0 + tx * 4;
    float bx_ = b1[n + 0] + b2[n + 0];
    float by_ = b1[n + 1] + b2[n + 1];
    float bz_ = b1[n + 2] + b2[n + 2];
    float bw_ = b1[n + 3] + b2[n + 3];
#pragma unroll
    for (int i = 0; i < 4; ++i) {
        int m = m0 + ty * 4 + i;
        float4 o;
        o.x = acc[i][0] + bx_; o.y = acc[i][1] + by_;
        o.z = acc[i][2] + bz_; o.w = acc[i][3] + bw_;
        *(float4*)(out + (size_t)m * HH + n) = o;
    }
}

// ---------------------------------------------------------------------------
// Fused 2-layer persistent recurrence, v7: in-group shuffle reduction.
//
// r11 forensics: v6's stall was the barrier+finalize serial chain (~1800cy/
// phase: finalize wave's LDS reduce + catch-up gates every barrier). v7
// removes the cross-wave reduce: each 16-lane group owns ONE row end-to-end.
// Group G (lanes x 32k each, k-slice [32j,32j+32)) computes:
//   aa = W_hh0[row]·h0  (layer-0 recurrence)
//   bb = W_ih1[row]·h0 + W_hh1[row]·h1  (layer-1, single accumulator)
// Reduction = 4 shfl_xor steps in-group; leader lane (j==0) does tanh +
// publish. NO red[] LDS, NO finalize waves, ONE barrier/phase (stage->read).
//
// Topology: 256 blocks = 16 chunks(4 batches) x 16 slices(32 rows), 512 thr,
// 1 block/CU. 4 phases/tick (one per batch); phase X's poll targets data
// published at phase X of tick t-1 -> slack = 3 phases (~3000cy) >> RT
// (~600-900cy): the hit regime (v6's 35%-busy profile shows 16-wide
// rendezvous polls hit; its cost was elsewhere).
//
// Weights: 96 floats/thread, pure VGPR. LDS h-staging: slices padded to 36
// floats (144B, 16B-aligned): b128 reads land <=2-way bank-aliased (free)
// instead of 16-way conflicted at stride-128B. Stage buffers double-buffered
// by phase parity: phase X reads buf[X&1]; phase X+2 rewrites it only after
// phase X+1's barrier, which no thread passes until all phase-X reads done.
//
// Exchange protocol unchanged (tag-in-data {f32,u32 tag} 8B relaxed agent
// atomics, 2-slot per-layer buffers hp0/hp1). Publish(tag t+1) for batch bX
// follows this block's poll(tag t) for bX within the same phase, so
// all-16-published-t => all-16-passed-poll(t-1) => the overwritten slot
// (tag t-1) is dead. Stale tags from a previous identical run carry
// identical values; 0xAA poison never matches tags 1..512.
// ---------------------------------------------------------------------------
typedef unsigned long long ull;

__device__ __forceinline__ void rec_phase7(
    int t, int bX, int grow, int j, int leader, int kown, int sa,
    const float* __restrict__ pre,
    const float4* wA, const float4* wI, const float4* wH, float bias1,
    ull* __restrict__ hp0, ull* __restrict__ hp1,
    float* __restrict__ s0buf, float* __restrict__ s1buf,  // this parity's [576]
    float* __restrict__ y, float& h0last, float& h1last) {
    // prefetch pre value (leader only; issued before the spin -> overlapped)
    float pv = 0.f;
    if (leader && t < SS) pv = pre[((size_t)bX * SS + t) * HH + grow];

    // poll own k in both layer buffers
    const ull* s0p = hp0 + (size_t)(t & 1) * BB * HH + (size_t)bX * HH + kown;
    const ull* s1p = hp1 + (size_t)(t & 1) * BB * HH + (size_t)bX * HH + kown;
    ull q0, q1;
    const unsigned tt = (unsigned)t;
    for (;;) {
        q0 = __hip_atomic_load(s0p, __ATOMIC_RELAXED, __HIP_MEMORY_SCOPE_AGENT);
        q1 = __hip_atomic_load(s1p, __ATOMIC_RELAXED, __HIP_MEMORY_SCOPE_AGENT);
        unsigned d = (((unsigned)(q0 >> 32)) ^ tt) | (((unsigned)(q1 >> 32)) ^ tt);
        if (d == 0) break;
    }
    // stage (padded layout: k -> 36*(k>>5) + (k&31)); conflict-free writes
    s0buf[sa] = __uint_as_float((unsigned)q0);
    s1buf[sa] = __uint_as_float((unsigned)q1);
    __syncthreads();   // the ONLY barrier this phase: stage -> read handoff

    // 3 matvec units over this lane's 32-k slice; h1 units share one acc
    const float4* x0 = (const float4*)&s0buf[36 * j];
    const float4* x1 = (const float4*)&s1buf[36 * j];
    float aa = 0.f, bb = 0.f;
#pragma unroll
    for (int i = 0; i < 8; ++i) {
        const float4 xv = x0[i];
        const float4 zv = x1[i];
        const float4 a4 = wA[i];
        const float4 i4 = wI[i];
        const float4 h4 = wH[i];
        aa = fmaf(a4.x, xv.x, aa); aa = fmaf(a4.y, xv.y, aa);
        aa = fmaf(a4.z, xv.z, aa); aa = fmaf(a4.w, xv.w, aa);
        bb = fmaf(i4.x, xv.x, bb); bb = fmaf(i4.y, xv.y, bb);
        bb = fmaf(i4.z, xv.z, bb); bb = fmaf(i4.w, xv.w, bb);
        bb = fmaf(h4.x, zv.x, bb); bb = fmaf(h4.y, zv.y, bb);
        bb = fmaf(h4.z, zv.z, bb); bb = fmaf(h4.w, zv.w, bb);
    }
    // in-group (16-lane) butterfly reduction — no LDS, no extra barrier
    aa += __shfl_xor(aa, 1); bb += __shfl_xor(bb, 1);
    aa += __shfl_xor(aa, 2); bb += __shfl_xor(bb, 2);
    aa += __shfl_xor(aa, 4); bb += __shfl_xor(bb, 4);
    aa += __shfl_xor(aa, 8); bb += __shfl_xor(bb, 8);

    // leader finalize: h0_X(t) and h1_X(t-1) for this group's row
    if (leader) {
        if (t < SS) {
            float h0v = tanhf(pv + aa);
            h0last = h0v;
            ull pk = ((ull)(unsigned)(t + 1) << 32) |
                     (ull)__float_as_uint(h0v);
            __hip_atomic_store(&hp0[(size_t)((t + 1) & 1) * BB * HH + (size_t)bX * HH + grow],
                               pk, __ATOMIC_RELAXED, __HIP_MEMORY_SCOPE_AGENT);
        }
        float h1v = tanhf(bb + bias1);
        h1last = h1v;
        y[((size_t)bX * SS + (t - 1)) * HH + grow] = h1v;
        if (t < SS) {
            ull pk = ((ull)(unsigned)(t + 1) << 32) |
                     (ull)__float_as_uint(h1v);
            __hip_atomic_store(&hp1[(size_t)((t + 1) & 1) * BB * HH + (size_t)bX * HH + grow],
                               pk, __ATOMIC_RELAXED, __HIP_MEMORY_SCOPE_AGENT);
        }
    }
}

__global__ __launch_bounds__(512, 2) void k_rec7(
    const float* __restrict__ pre,       // [B][S][H] layer0 input projection
    const float* __restrict__ Whh0,
    const float* __restrict__ Wih1,
    const float* __restrict__ Whh1,
    const float* __restrict__ b_ih1,
    const float* __restrict__ b_hh1,
    float* __restrict__ y,               // [B][S][H] layer1 output
    float* __restrict__ hlast,           // [2][B][H]
    ull* __restrict__ hp0,
    ull* __restrict__ hp1) {
    // staging: [parity][layer][16 slices x 36 floats] — 9216 B total
    __shared__ __align__(16) float stg[2][2][576];

    const int tid = threadIdx.x;
    const int j = tid & 15;              // lane within group (k-slice [32j,32j+32))
    const int G = tid >> 4;              // group 0..31 = row within slice
    const int bid = blockIdx.x;
    const int g = bid & 15;              // row slice 0..15 (32 rows)
    const int c = bid >> 4;              // chunk 0..15 (4 batches)
    const int grow = g * 32 + G;         // this group's output row
    const int leader = (j == 0);
    const int kown = tid;                // polled k (both layers)
    const int sa = 36 * (kown >> 5) + (kown & 31);   // staging address
    const int b0 = c * 4;

    // per-lane weights: row grow, k in [32j,32j+32), 3 units = 96 floats (VGPR)
    float4 wA[8], wI[8], wH[8];
    {
        const float* pA = Whh0 + (size_t)grow * HH + 32 * j;
        const float* pI = Wih1 + (size_t)grow * HH + 32 * j;
        const float* pH = Whh1 + (size_t)grow * HH + 32 * j;
#pragma unroll
        for (int i = 0; i < 8; ++i) {
            wA[i] = *(const float4*)(pA + i * 4);
            wI[i] = *(const float4*)(pI + i * 4);
            wH[i] = *(const float4*)(pH + i * 4);
        }
    }
    const float bias1 = b_ih1[grow] + b_hh1[grow];

    // ---- prologue: per batch, h0(0)=tanh(pre[0]) tag 1; h1(-1)=0 tag 1 ----
    float h0l[4] = {0.f, 0.f, 0.f, 0.f};   // static-indexed via unroll below
    float h1l[4] = {0.f, 0.f, 0.f, 0.f};
    if (leader) {
#pragma unroll
        for (int X = 0; X < 4; ++X) {
            const int bX = b0 + X;
            float p0 = pre[(size_t)bX * SS * HH + grow];
            float v = tanhf(p0);
            h0l[X] = v;
            ull pk = (1ULL << 32) | (ull)__float_as_uint(v);
            __hip_atomic_store(&hp0[(size_t)1 * BB * HH + (size_t)bX * HH + grow],
                               pk, __ATOMIC_RELAXED, __HIP_MEMORY_SCOPE_AGENT);
            __hip_atomic_store(&hp1[(size_t)1 * BB * HH + (size_t)bX * HH + grow],
                               (1ULL << 32), __ATOMIC_RELAXED, __HIP_MEMORY_SCOPE_AGENT);
        }
    }

    for (int t = 1; t <= SS; ++t) {
        // 4 phases; phase X's tag-t data published 3 phases earlier
        rec_phase7(t, b0 + 0, grow, j, leader, kown, sa, pre, wA, wI, wH, bias1,
                   hp0, hp1, stg[0][0], stg[0][1], y, h0l[0], h1l[0]);
        rec_phase7(t, b0 + 1, grow, j, leader, kown, sa, pre, wA, wI, wH, bias1,
                   hp0, hp1, stg[1][0], stg[1][1], y, h0l[1], h1l[1]);
        rec_phase7(t, b0 + 2, grow, j, leader, kown, sa, pre, wA, wI, wH, bias1,
                   hp0, hp1, stg[0][0], stg[0][1], y, h0l[2], h1l[2]);
        rec_phase7(t, b0 + 3, grow, j, leader, kown, sa, pre, wA, wI, wH, bias1,
                   hp0, hp1, stg[1][0], stg[1][1], y, h0l[3], h1l[3]);
    }

    if (leader) {
#pragma unroll
        for (int X = 0; X < 4; ++X) {
            const int bX = b0 + X;
            hlast[(size_t)bX * HH + grow] = h0l[X];                       // layer0
            hlast[(size_t)BB * HH + (size_t)bX * HH + grow] = h1l[X];     // layer1
        }
    }
}

// ---------------------------------------------------------------------------
extern "C" void kernel_launch(void* const* d_in, const int* in_sizes, int n_in,
                              void* d_out, int out_size, void* d_ws, size_t ws_size,
                              hipStream_t stream) {
    const int*   src   = (const int*)d_in[0];
    const float* emb   = (const float*)d_in[1];
    const float* W_ih0 = (const float*)d_in[2];
    const float* W_hh0 = (const float*)d_in[3];
    const float* b_ih0 = (const float*)d_in[4];
    const float* b_hh0 = (const float*)d_in[5];
    const float* W_ih1 = (const float*)d_in[6];
    const float* W_hh1 = (const float*)d_in[7];
    const float* b_ih1 = (const float*)d_in[8];
    const float* b_hh1 = (const float*)d_in[9];

    float* out   = (float*)d_out;
    float* y_out = out;                               // [B][S][H] (layer1 y)
    float* hlast = out + (size_t)BB * SS * HH;        // [2][B][H]

    float* ws  = (float*)d_ws;
    float* pre = ws;                                  // [B][S][H] layer0 proj
    ull* hp0 = (ull*)(ws + (size_t)BB * SS * HH);
    ull* hp1 = hp0 + (size_t)2 * BB * HH;

    // Layer-0 input projection (embedding gather fused in)
    k_proj<EE><<<dim3(512, 8), 256, 0, stream>>>(nullptr, src, emb, W_ih0,
                                                 b_ih0, b_hh0, pre);
    // Fused 2-layer recurrence: in-group shuffle reduce, 1 barrier/phase
    k_rec7<<<256, 512, 0, stream>>>(pre, W_hh0, W_ih1, W_hh1, b_ih1, b_hh1,
                                    y_out, hlast, hp0, hp1);
}